// Round 2
// baseline (340.087 us; speedup 1.0000x reference)
//
#include <hip/hip_runtime.h>

typedef _Float16 f16;
typedef f16 f16x8 __attribute__((ext_vector_type(8)));
typedef f16 f16x4 __attribute__((ext_vector_type(4)));
typedef float f32x4 __attribute__((ext_vector_type(4)));

#define NROWS 16384
#define KDIM  1024
#define IDIM  256
#define ODIM  512

// ---- workspace layout (bytes) ----
// logits: 16384*3*4 = 196608  -> region [0, 262144)
// WT_att: 3 * 256*1024*2  = 1572864 -> [262144, 1835008)
// WT_tr : 3 * 512*1024*2  = 3145728 -> [1835008, 4980736)
#define WS_LOGITS 0
#define WS_WT_ATT 262144
#define WS_WT_TR  1835008

__device__ __forceinline__ float fast_tanhf(float x) {
    float ax = fabsf(x);
    float e = __expf(-2.0f * ax);          // in (0,1], overflow-safe
    float t = (1.0f - e) / (1.0f + e);
    return copysignf(t, x);
}

// ---------------------------------------------------------------------------
// Kernel 0: transpose + f16-convert the six weight matrices: W[K][N] -> WT[N][K]
// ---------------------------------------------------------------------------
__global__ __launch_bounds__(256) void transpose_w_kernel(
    const float* __restrict__ Wa0, const float* __restrict__ Wa1, const float* __restrict__ Wa2,
    const float* __restrict__ Wt0, const float* __restrict__ Wt1, const float* __restrict__ Wt2,
    f16* __restrict__ wta, f16* __restrict__ wtt)
{
    __shared__ float tile[64][65];
    int mat = blockIdx.y;  // 0..2 att, 3..5 tr
    const float* src;
    f16* dst;
    int N;
    if (mat < 3) {
        src = (mat == 0) ? Wa0 : (mat == 1) ? Wa1 : Wa2;
        dst = wta + (size_t)mat * IDIM * KDIM;
        N = IDIM;
    } else {
        int m = mat - 3;
        src = (m == 0) ? Wt0 : (m == 1) ? Wt1 : Wt2;
        dst = wtt + (size_t)m * ODIM * KDIM;
        N = ODIM;
    }
    int ntiles = (N / 64) * (KDIM / 64);
    int tilei = blockIdx.x;
    if (tilei >= ntiles) return;  // uniform per block
    int tn = tilei / (KDIM / 64);
    int tk = tilei % (KDIM / 64);
    int n0 = tn * 64, k0 = tk * 64;
    int t = threadIdx.x;

    #pragma unroll
    for (int j = 0; j < 16; ++j) {
        int f = j * 256 + t;
        int r = f >> 6, c = f & 63;
        tile[r][c] = src[(size_t)(k0 + r) * N + n0 + c];
    }
    __syncthreads();
    #pragma unroll
    for (int j = 0; j < 8; ++j) {
        int p = j * 256 + t;
        int n = p >> 5, kp = p & 31;
        union { f16 h[2]; unsigned int u; } pk;
        pk.h[0] = (f16)tile[2 * kp][n];
        pk.h[1] = (f16)tile[2 * kp + 1][n];
        *(unsigned int*)(&dst[(size_t)(n0 + n) * KDIM + k0 + 2 * kp]) = pk.u;
    }
}

// ---------------------------------------------------------------------------
// Kernel 1: logits[b, br] = tanh(x_br @ W_att_br + b_att_br) @ v
// One block = 64 rows x one branch. BM=64, BN=256(full), BK=64, 4 waves.
// ---------------------------------------------------------------------------
__global__ __launch_bounds__(256) void logits_kernel(
    const float* __restrict__ x0, const float* __restrict__ x1, const float* __restrict__ x2,
    const float* __restrict__ ba0, const float* __restrict__ ba1, const float* __restrict__ ba2,
    const f16* __restrict__ wta, const float* __restrict__ v,
    float* __restrict__ logits)
{
    __shared__ __align__(16) char sA[64 * 128];    // 64 rows x 64 f16 (swizzled)
    __shared__ __align__(16) char sB[256 * 128];   // 256 n-rows x 64 f16 (swizzled)
    __shared__ float red[4][64];

    int br = blockIdx.y;
    const float* x  = (br == 0) ? x0 : (br == 1) ? x1 : x2;
    const float* ba = (br == 0) ? ba0 : (br == 1) ? ba1 : ba2;
    const f16* WT = wta + (size_t)br * IDIM * KDIM;
    int m0 = blockIdx.x * 64;
    int t = threadIdx.x;
    int l = t & 63;
    int w = t >> 6;

    f32x4 acc[4][4];
    #pragma unroll
    for (int i = 0; i < 4; ++i)
        #pragma unroll
        for (int j = 0; j < 4; ++j) acc[i][j] = (f32x4)0.0f;

    const int arow = t >> 4;   // 0..15
    const int ac4  = t & 15;   // float4 index within 64-col row

    for (int kt = 0; kt < KDIM / 64; ++kt) {
        int k0 = kt * 64;
        // ---- global loads to regs ----
        float4 av[4];
        #pragma unroll
        for (int j = 0; j < 4; ++j) {
            int r = j * 16 + arow;
            av[j] = *(const float4*)(x + (size_t)(m0 + r) * KDIM + k0 + ac4 * 4);
        }
        f16x8 bv[8];
        #pragma unroll
        for (int j = 0; j < 8; ++j) {
            int q = j * 256 + t;
            int n = q >> 3, c = q & 7;
            bv[j] = *(const f16x8*)(WT + (size_t)n * KDIM + k0 + c * 8);
        }
        __syncthreads();  // prior compute done before overwriting LDS
        // ---- LDS writes (XOR-swizzled, G4: 128B rows) ----
        #pragma unroll
        for (int j = 0; j < 4; ++j) {
            int r = j * 16 + arow;
            f16x4 hv;
            hv[0] = (f16)av[j].x; hv[1] = (f16)av[j].y;
            hv[2] = (f16)av[j].z; hv[3] = (f16)av[j].w;
            int byte = r * 128 + ((((ac4 >> 1) ^ (r & 7)) << 4) | ((ac4 & 1) << 3));
            *(f16x4*)(sA + byte) = hv;
        }
        #pragma unroll
        for (int j = 0; j < 8; ++j) {
            int q = j * 256 + t;
            int n = q >> 3, c = q & 7;
            int byte = n * 128 + ((c ^ (n & 7)) << 4);
            *(f16x8*)(sB + byte) = bv[j];
        }
        __syncthreads();
        // ---- MFMA ----
        #pragma unroll
        for (int kk = 0; kk < 2; ++kk) {
            f16x8 af[4], bf[4];
            #pragma unroll
            for (int fm = 0; fm < 4; ++fm) {
                int row = fm * 16 + (l & 15);
                int ch = kk * 4 + (l >> 4);
                af[fm] = *(const f16x8*)(sA + row * 128 + ((ch ^ (row & 7)) << 4));
            }
            #pragma unroll
            for (int fn = 0; fn < 4; ++fn) {
                int nr = w * 64 + fn * 16 + (l & 15);
                int ch = kk * 4 + (l >> 4);
                bf[fn] = *(const f16x8*)(sB + nr * 128 + ((ch ^ (nr & 7)) << 4));
            }
            #pragma unroll
            for (int fm = 0; fm < 4; ++fm)
                #pragma unroll
                for (int fn = 0; fn < 4; ++fn)
                    acc[fm][fn] = __builtin_amdgcn_mfma_f32_16x16x32_f16(
                        af[fm], bf[fn], acc[fm][fn], 0, 0, 0);
        }
    }

    // ---- epilogue: tanh(acc + b_att) . v, reduce over 256 cols ----
    float vv[4], bb[4];
    #pragma unroll
    for (int fn = 0; fn < 4; ++fn) {
        int col = w * 64 + fn * 16 + (l & 15);
        vv[fn] = v[col];
        bb[fn] = ba[col];
    }
    #pragma unroll
    for (int fm = 0; fm < 4; ++fm) {
        #pragma unroll
        for (int reg = 0; reg < 4; ++reg) {
            float s = 0.f;
            #pragma unroll
            for (int fn = 0; fn < 4; ++fn)
                s += fast_tanhf(acc[fm][fn][reg] + bb[fn]) * vv[fn];
            #pragma unroll
            for (int d = 1; d < 16; d <<= 1)
                s += __shfl_xor(s, d, 64);
            if ((l & 15) == 0) {
                int row = fm * 16 + (l >> 4) * 4 + reg;
                red[w][row] = s;
            }
        }
    }
    __syncthreads();
    if (t < 64) {
        float lg = red[0][t] + red[1][t] + red[2][t] + red[3][t];
        logits[(size_t)(m0 + t) * 3 + br] = lg;
    }
}

// ---------------------------------------------------------------------------
// Kernel 2: out = sum_i soft[:,i] * (x_i @ W_tr_i + b_tr_i)
// Softmax weight folded into A at convert time. BM=64, BN=256, K=3x1024.
// Grid: (n-tiles=2, m-tiles=256) — n-fast so each XCD keeps one B-panel
// L2-resident and x-row-panels are shared between adjacent dispatches (L3-hot).
// ---------------------------------------------------------------------------
__global__ __launch_bounds__(256) void out_kernel(
    const float* __restrict__ x0, const float* __restrict__ x1, const float* __restrict__ x2,
    const float* __restrict__ bt0, const float* __restrict__ bt1, const float* __restrict__ bt2,
    const f16* __restrict__ wtt, const float* __restrict__ logits,
    float* __restrict__ out)
{
    __shared__ __align__(16) char sA[64 * 128];
    __shared__ __align__(16) char sB[256 * 128];
    __shared__ float sS[64][4];

    int m0 = blockIdx.y * 64;
    int n0 = blockIdx.x * 256;
    int t = threadIdx.x;
    int l = t & 63;
    int w = t >> 6;

    if (t < 64) {
        float l0 = logits[(size_t)(m0 + t) * 3 + 0];
        float l1 = logits[(size_t)(m0 + t) * 3 + 1];
        float l2 = logits[(size_t)(m0 + t) * 3 + 2];
        float mx = fmaxf(l0, fmaxf(l1, l2));
        float e0 = __expf(l0 - mx), e1 = __expf(l1 - mx), e2 = __expf(l2 - mx);
        float inv = 1.0f / (e0 + e1 + e2);
        sS[t][0] = e0 * inv; sS[t][1] = e1 * inv; sS[t][2] = e2 * inv;
    }
    __syncthreads();

    f32x4 acc[4][4];
    #pragma unroll
    for (int i = 0; i < 4; ++i)
        #pragma unroll
        for (int j = 0; j < 4; ++j) acc[i][j] = (f32x4)0.0f;

    const int arow = t >> 4;
    const int ac4  = t & 15;

    for (int brn = 0; brn < 3; ++brn) {
        const float* x = (brn == 0) ? x0 : (brn == 1) ? x1 : x2;
        const f16* WT = wtt + (size_t)brn * ODIM * KDIM;
        float sreg[4];
        #pragma unroll
        for (int j = 0; j < 4; ++j) sreg[j] = sS[j * 16 + arow][brn];

        for (int kt = 0; kt < KDIM / 64; ++kt) {
            int k0 = kt * 64;
            float4 av[4];
            #pragma unroll
            for (int j = 0; j < 4; ++j) {
                int r = j * 16 + arow;
                av[j] = *(const float4*)(x + (size_t)(m0 + r) * KDIM + k0 + ac4 * 4);
            }
            f16x8 bv[8];
            #pragma unroll
            for (int j = 0; j < 8; ++j) {
                int q = j * 256 + t;
                int n = q >> 3, c = q & 7;
                bv[j] = *(const f16x8*)(WT + (size_t)(n0 + n) * KDIM + k0 + c * 8);
            }
            __syncthreads();
            #pragma unroll
            for (int j = 0; j < 4; ++j) {
                int r = j * 16 + arow;
                float s = sreg[j];
                f16x4 hv;
                hv[0] = (f16)(av[j].x * s); hv[1] = (f16)(av[j].y * s);
                hv[2] = (f16)(av[j].z * s); hv[3] = (f16)(av[j].w * s);
                int byte = r * 128 + ((((ac4 >> 1) ^ (r & 7)) << 4) | ((ac4 & 1) << 3));
                *(f16x4*)(sA + byte) = hv;
            }
            #pragma unroll
            for (int j = 0; j < 8; ++j) {
                int q = j * 256 + t;
                int n = q >> 3, c = q & 7;
                int byte = n * 128 + ((c ^ (n & 7)) << 4);
                *(f16x8*)(sB + byte) = bv[j];
            }
            __syncthreads();
            #pragma unroll
            for (int kk = 0; kk < 2; ++kk) {
                f16x8 af[4], bf[4];
                #pragma unroll
                for (int fm = 0; fm < 4; ++fm) {
                    int row = fm * 16 + (l & 15);
                    int ch = kk * 4 + (l >> 4);
                    af[fm] = *(const f16x8*)(sA + row * 128 + ((ch ^ (row & 7)) << 4));
                }
                #pragma unroll
                for (int fn = 0; fn < 4; ++fn) {
                    int nr = w * 64 + fn * 16 + (l & 15);
                    int ch = kk * 4 + (l >> 4);
                    bf[fn] = *(const f16x8*)(sB + nr * 128 + ((ch ^ (nr & 7)) << 4));
                }
                #pragma unroll
                for (int fm = 0; fm < 4; ++fm)
                    #pragma unroll
                    for (int fn = 0; fn < 4; ++fn)
                        acc[fm][fn] = __builtin_amdgcn_mfma_f32_16x16x32_f16(
                            af[fm], bf[fn], acc[fm][fn], 0, 0, 0);
            }
        }
    }

    // ---- epilogue: + sum_i s_i * b_tr_i, fp32 store ----
    float btc[3][4];
    #pragma unroll
    for (int fn = 0; fn < 4; ++fn) {
        int col = n0 + w * 64 + fn * 16 + (l & 15);
        btc[0][fn] = bt0[col];
        btc[1][fn] = bt1[col];
        btc[2][fn] = bt2[col];
    }
    #pragma unroll
    for (int fm = 0; fm < 4; ++fm) {
        #pragma unroll
        for (int reg = 0; reg < 4; ++reg) {
            int row = fm * 16 + (l >> 4) * 4 + reg;
            float s0 = sS[row][0], s1 = sS[row][1], s2 = sS[row][2];
            #pragma unroll
            for (int fn = 0; fn < 4; ++fn) {
                int col = n0 + w * 64 + fn * 16 + (l & 15);
                float val = acc[fm][fn][reg]
                          + s0 * btc[0][fn] + s1 * btc[1][fn] + s2 * btc[2][fn];
                out[(size_t)(m0 + row) * ODIM + col] = val;
            }
        }
    }
}

// ---------------------------------------------------------------------------
extern "C" void kernel_launch(void* const* d_in, const int* in_sizes, int n_in,
                              void* d_out, int out_size, void* d_ws, size_t ws_size,
                              hipStream_t stream)
{
    (void)in_sizes; (void)n_in; (void)out_size; (void)ws_size;
    const float* x0  = (const float*)d_in[0];
    const float* Wa0 = (const float*)d_in[1];
    const float* ba0 = (const float*)d_in[2];
    const float* Wt0 = (const float*)d_in[3];
    const float* bt0 = (const float*)d_in[4];
    const float* x1  = (const float*)d_in[5];
    const float* Wa1 = (const float*)d_in[6];
    const float* ba1 = (const float*)d_in[7];
    const float* Wt1 = (const float*)d_in[8];
    const float* bt1 = (const float*)d_in[9];
    const float* x2  = (const float*)d_in[10];
    const float* Wa2 = (const float*)d_in[11];
    const float* ba2 = (const float*)d_in[12];
    const float* Wt2 = (const float*)d_in[13];
    const float* bt2 = (const float*)d_in[14];
    const float* v   = (const float*)d_in[15];

    char* ws = (char*)d_ws;
    float* logits = (float*)(ws + WS_LOGITS);
    f16* wta = (f16*)(ws + WS_WT_ATT);
    f16* wtt = (f16*)(ws + WS_WT_TR);
    float* out = (float*)d_out;

    transpose_w_kernel<<<dim3(128, 6), 256, 0, stream>>>(Wa0, Wa1, Wa2, Wt0, Wt1, Wt2, wta, wtt);
    logits_kernel<<<dim3(NROWS / 64, 3), 256, 0, stream>>>(x0, x1, x2, ba0, ba1, ba2, wta, v, logits);
    out_kernel<<<dim3(2, NROWS / 64), 256, 0, stream>>>(x0, x1, x2, bt0, bt1, bt2, wtt, logits, out);
}